// Round 7
// baseline (522.528 us; speedup 1.0000x reference)
//
#include <hip/hip_runtime.h>

// ---------------------------------------------------------------------------
// GAT 3-layer classifier, bf16 intermediate storage + MFMA GEMMs.
//   CSR build (count / multi-block scan / scatter) -- edges grouped by dst
//   per layer: mfma-gemm(h,W)+attn-coef epilogue -> single-pass aggregate
//   pool (sorted batch, chunked) -> classifier GEMM
// All math f32 in registers; h stored bf16 (manual RNE).
// R6: single-pass softmax (no max-shift; |e| O(1)), attn fused in GEMM.
// R7: aggregate edge-split 2 waves/node (halves serial gather rounds;
//     LDS combine); log2e folded into as/ad (exp2 in hot loop);
//     xcast fused into GEMM-1 staging (f32 A converted in-register).
// ---------------------------------------------------------------------------

typedef __attribute__((ext_vector_type(8))) __bf16 bf16x8;
typedef __attribute__((ext_vector_type(4))) float f32x4;

#define LOG2E 1.44269504f

static __device__ __forceinline__ unsigned short f2bf(float f) {
    unsigned u = __float_as_uint(f);
    unsigned r = (u + 0x7fffu + ((u >> 16) & 1u)) >> 16;
    return (unsigned short)r;
}
static __device__ __forceinline__ float bf2f(unsigned short s) {
    return __uint_as_float(((unsigned)s) << 16);
}

// ============================ CSR build ====================================
__global__ void count_edges(const int* __restrict__ ei, int* __restrict__ deg,
                            int E, int N) {
    int i = blockIdx.x * blockDim.x + threadIdx.x;
    int tot = E + N;
    if (i >= tot) return;
    int dst = (i < E) ? ei[E + i] : (i - E);
    atomicAdd(&deg[dst], 1);
}

__global__ __launch_bounds__(256) void scan_partial(const int* __restrict__ deg,
                                                    int* __restrict__ rowptr,
                                                    int* __restrict__ blockSums, int N) {
    int t = threadIdx.x;
    int lane = t & 63, wv = t >> 6;
    int base = blockIdx.x * 1024 + t * 4;
    int v[4];
#pragma unroll
    for (int j = 0; j < 4; ++j) v[j] = (base + j < N) ? deg[base + j] : 0;
    int local = v[0] + v[1] + v[2] + v[3];
    int x = local;
#pragma unroll
    for (int off = 1; off < 64; off <<= 1) {
        int y = __shfl_up(x, off);
        if (lane >= off) x += y;
    }
    __shared__ int wsum[4];
    if (lane == 63) wsum[wv] = x;
    __syncthreads();
    int woff = 0;
    for (int i = 0; i < wv; ++i) woff += wsum[i];
    int run = woff + x - local;
#pragma unroll
    for (int j = 0; j < 4; ++j) {
        if (base + j < N) rowptr[base + j] = run;
        run += v[j];
    }
    if (t == 255) blockSums[blockIdx.x] = woff + x;
}

__global__ void scan_blocks(int* __restrict__ blockSums, int* __restrict__ rowptr,
                            int NB, int N) {
    int lane = threadIdx.x;  // 64 threads
    int carry = 0;
    for (int b0 = 0; b0 < NB; b0 += 64) {
        int i = b0 + lane;
        int v = (i < NB) ? blockSums[i] : 0;
        int x = v;
#pragma unroll
        for (int off = 1; off < 64; off <<= 1) {
            int y = __shfl_up(x, off);
            if (lane >= off) x += y;
        }
        if (i < NB) blockSums[i] = carry + x - v;
        carry += __shfl(x, 63);
    }
    if (lane == 0) rowptr[N] = carry;
}

__global__ void add_offsets(int* __restrict__ rowptr, const int* __restrict__ blockOffs,
                            int N) {
    int i = blockIdx.x * blockDim.x + threadIdx.x;
    if (i < N) rowptr[i] += blockOffs[i >> 10];
}

__global__ void scatter_edges(const int* __restrict__ ei, const int* __restrict__ rowptr,
                              int* __restrict__ fill, int* __restrict__ srcs, int E, int N) {
    int i = blockIdx.x * blockDim.x + threadIdx.x;
    int tot = E + N;
    if (i >= tot) return;
    int src, dst;
    if (i < E) { src = ei[i]; dst = ei[E + i]; }
    else       { src = i - E; dst = i - E; }
    int pos = atomicAdd(&fill[dst], 1);
    srcs[rowptr[dst] + pos] = src;
}

// ============================ casts ========================================
// Wt[n*K+k] = bf16(W[k*N+n])
__global__ void wcast(const float* __restrict__ W, unsigned short* __restrict__ Wt,
                      int K, int N) {
    int i = blockIdx.x * blockDim.x + threadIdx.x;
    if (i >= N * K) return;
    int n = i / K, k = i - n * K;
    Wt[i] = f2bf(W[(size_t)k * N + n]);
}

// ============================ MFMA GEMM + attn epilogue ====================
// C[M,N](bf16) = A[M,K] @ Bt[N,K](bf16)^T.  AF32: A is f32, converted while
// staging (fuses the xcast).  128x128 tile, BK=32, 4 waves, 64x64/wave.
// Epilogue: wave's 64-col span == one head; as/ad dots from f32 accumulators,
// PRE-SCALED by log2(e) so the aggregate can use exp2 (leaky_relu commutes
// with positive scaling).
#define BM 128
#define BN 128
#define BK 32
#define LDK 40  // padded row stride (elements); 80B, 16B-aligned

template <bool AF32>
__global__ __launch_bounds__(256) void gemm_bf16(const void* __restrict__ Av,
                                                 const unsigned short* __restrict__ Bt,
                                                 unsigned short* __restrict__ C,
                                                 const float* __restrict__ a_src,
                                                 const float* __restrict__ a_dst,
                                                 float* __restrict__ as_o,
                                                 float* __restrict__ ad_o,
                                                 int M, int N, int K, int H) {
    __shared__ unsigned short As[BM * LDK];
    __shared__ unsigned short Bs[BN * LDK];
    int t = threadIdx.x;
    int bm = blockIdx.y * BM, bn = blockIdx.x * BN;
    int wave = t >> 6, lane = t & 63;
    int wm = (wave >> 1) * 64, wn = (wave & 1) * 64;
    int quad = lane >> 4, mr = lane & 15;

    f32x4 zero = {0.f, 0.f, 0.f, 0.f};
    f32x4 acc[4][4];
#pragma unroll
    for (int i = 0; i < 4; ++i)
#pragma unroll
        for (int j = 0; j < 4; ++j) acc[i][j] = zero;

    for (int k0 = 0; k0 < K; k0 += BK) {
        ushort4 ua[2][2];   // staged A (bf16), 2 segs x 8 elems
        float4 vb[2];
#pragma unroll
        for (int h = 0; h < 2; ++h) {
            int s = t + h * 256;
            int row = s >> 2, seg = (s & 3) * 8;
            int gra = bm + row;
            if (AF32) {
                const float* Af = (const float*)Av;
                float4 lo = make_float4(0.f, 0.f, 0.f, 0.f), hi = lo;
                if (gra < M) {
                    lo = *(const float4*)&Af[(size_t)gra * K + k0 + seg];
                    hi = *(const float4*)&Af[(size_t)gra * K + k0 + seg + 4];
                }
                ua[h][0] = make_ushort4(f2bf(lo.x), f2bf(lo.y), f2bf(lo.z), f2bf(lo.w));
                ua[h][1] = make_ushort4(f2bf(hi.x), f2bf(hi.y), f2bf(hi.z), f2bf(hi.w));
            } else {
                const unsigned short* Ab = (const unsigned short*)Av;
                float4 va = make_float4(0.f, 0.f, 0.f, 0.f);
                if (gra < M) va = *(const float4*)&Ab[(size_t)gra * K + k0 + seg];
                ua[h][0] = *(ushort4*)&va.x;
                ua[h][1] = *(ushort4*)&va.z;
            }
            int grb = bn + row;
            vb[h] = make_float4(0.f, 0.f, 0.f, 0.f);
            if (grb < N) vb[h] = *(const float4*)&Bt[(size_t)grb * K + k0 + seg];
        }
        __syncthreads();
#pragma unroll
        for (int h = 0; h < 2; ++h) {
            int s = t + h * 256;
            int row = s >> 2, seg = (s & 3) * 8;
            *(ushort4*)&As[row * LDK + seg]     = ua[h][0];
            *(ushort4*)&As[row * LDK + seg + 4] = ua[h][1];
            *(float4*)&Bs[row * LDK + seg] = vb[h];
        }
        __syncthreads();

        bf16x8 af[4], bfr[4];
#pragma unroll
        for (int i = 0; i < 4; ++i) {
            af[i]  = *(bf16x8*)&As[(wm + i * 16 + mr) * LDK + quad * 8];
            bfr[i] = *(bf16x8*)&Bs[(wn + i * 16 + mr) * LDK + quad * 8];
        }
#pragma unroll
        for (int i = 0; i < 4; ++i)
#pragma unroll
            for (int j = 0; j < 4; ++j)
                acc[i][j] = __builtin_amdgcn_mfma_f32_16x16x32_bf16(af[i], bfr[j], acc[i][j], 0, 0, 0);
    }

    // attn coefficients: this wave's 64 cols == head (bn+wn)/64
    int colbase = bn + wn;
    if (colbase + 64 <= N) {
        int head = colbase >> 6;
        float asv[4], adv[4];
#pragma unroll
        for (int j = 0; j < 4; ++j) {
            asv[j] = a_src[head * 64 + j * 16 + mr];
            adv[j] = a_dst[head * 64 + j * 16 + mr];
        }
#pragma unroll
        for (int i = 0; i < 4; ++i) {
#pragma unroll
            for (int r = 0; r < 4; ++r) {
                float ps = acc[i][0][r] * asv[0] + acc[i][1][r] * asv[1]
                         + acc[i][2][r] * asv[2] + acc[i][3][r] * asv[3];
                float pd = acc[i][0][r] * adv[0] + acc[i][1][r] * adv[1]
                         + acc[i][2][r] * adv[2] + acc[i][3][r] * adv[3];
#pragma unroll
                for (int off2 = 1; off2 < 16; off2 <<= 1) {
                    ps += __shfl_xor(ps, off2);
                    pd += __shfl_xor(pd, off2);
                }
                int grow = bm + wm + i * 16 + quad * 4 + r;
                if (mr == 0 && grow < M) {
                    as_o[(size_t)grow * H + head] = ps * LOG2E;
                    ad_o[(size_t)grow * H + head] = pd * LOG2E;
                }
            }
        }
    }

    // C store: C/D layout col=lane&15, row=quad*4+reg
#pragma unroll
    for (int i = 0; i < 4; ++i) {
#pragma unroll
        for (int r = 0; r < 4; ++r) {
            int grow = bm + wm + i * 16 + quad * 4 + r;
            if (grow >= M) continue;
#pragma unroll
            for (int j = 0; j < 4; ++j) {
                int gcol = bn + wn + j * 16 + mr;
                if (gcol < N) C[(size_t)grow * N + gcol] = f2bf(acc[i][j][r]);
            }
        }
    }
}

// ============================ aggregation ==================================
// Single-pass unnormalized softmax: out = sum(exp(e)*h) / (sum(exp(e))+eps).
// as/ad are pre-scaled by log2(e), so exp(leaky(x)) == exp2(leaky(scaled x)).
// R7: TWO waves per node, each taking a contiguous half of the edge range
// (halves the serial gather-round count); partials combined via LDS.
// Block = 256 thr = 4 waves = 2 nodes.
template <int H, int VPL, bool OUTF32>
__global__ __launch_bounds__(256) void gat_aggregate(const unsigned short* __restrict__ hbuf,
                                                     const float* __restrict__ as_i,
                                                     const float* __restrict__ ad_i,
                                                     const int* __restrict__ rowptr,
                                                     const int* __restrict__ srcs,
                                                     const float* __restrict__ bias,
                                                     void* __restrict__ out_v, int N) {
    const int HC = 64 * VPL;
    __shared__ float part[2][64][VPL + 1];
    int t = threadIdx.x;
    int wave = t >> 6, lane = t & 63;
    int nl = wave >> 1, half = wave & 1;
    int node = blockIdx.x * 2 + nl;
    bool valid = node < N;
    const int hd_lane = (lane * VPL) >> 6;

    int row = 0, end = 0;
    if (valid) { row = rowptr[node]; end = rowptr[node + 1]; }
    int len = end - row;
    int h0 = (len + 1) >> 1;
    int lo = (half == 0) ? row : row + h0;
    int hi = (half == 0) ? row + h0 : end;

    float advh = valid ? ad_i[(size_t)node * H + hd_lane] : 0.f;

    float acc[VPL];
#pragma unroll
    for (int j = 0; j < VPL; ++j) acc[j] = 0.f;
    float l = 0.f;

    const int U = 8;
    int i = lo;
    for (; i + U <= hi; i += U) {
        int s[U];
        float cf[U];
#pragma unroll
        for (int u = 0; u < U; ++u) s[u] = srcs[i + u];
#pragma unroll
        for (int u = 0; u < U; ++u) cf[u] = as_i[(size_t)s[u] * H + hd_lane];
        if (VPL == 4) {
            ushort4 r[U];
#pragma unroll
            for (int u = 0; u < U; ++u)
                r[u] = *(const ushort4*)&hbuf[(size_t)s[u] * HC + lane * 4];
#pragma unroll
            for (int u = 0; u < U; ++u) {
                float e = cf[u] + advh;
                e = (e > 0.f) ? e : 0.2f * e;
                float wgt = exp2f(e);
                l += wgt;
                acc[0] += wgt * bf2f(r[u].x);
                acc[1] += wgt * bf2f(r[u].y);
                acc[2] += wgt * bf2f(r[u].z);
                acc[3] += wgt * bf2f(r[u].w);
            }
        } else {
            unsigned short r[U];
#pragma unroll
            for (int u = 0; u < U; ++u) r[u] = hbuf[(size_t)s[u] * HC + lane];
#pragma unroll
            for (int u = 0; u < U; ++u) {
                float e = cf[u] + advh;
                e = (e > 0.f) ? e : 0.2f * e;
                float wgt = exp2f(e);
                l += wgt;
                acc[0] += wgt * bf2f(r[u]);
            }
        }
    }
    for (; i < hi; ++i) {
        int s = srcs[i];
        float e = as_i[(size_t)s * H + hd_lane] + advh;
        e = (e > 0.f) ? e : 0.2f * e;
        float wgt = exp2f(e);
        l += wgt;
        if (VPL == 4) {
            ushort4 hv = *(const ushort4*)&hbuf[(size_t)s * HC + lane * 4];
            acc[0] += wgt * bf2f(hv.x); acc[1] += wgt * bf2f(hv.y);
            acc[2] += wgt * bf2f(hv.z); acc[3] += wgt * bf2f(hv.w);
        } else {
            acc[0] += wgt * bf2f(hbuf[(size_t)s * HC + lane]);
        }
    }

    if (half == 1) {
#pragma unroll
        for (int j = 0; j < VPL; ++j) part[nl][lane][j] = acc[j];
        part[nl][lane][VPL] = l;
    }
    __syncthreads();
    if (half == 1 || !valid) return;

#pragma unroll
    for (int j = 0; j < VPL; ++j) acc[j] += part[nl][lane][j];
    l += part[nl][lane][VPL];

    float inv_l = 1.f / (l + 1e-16f);
    float vals[VPL];
#pragma unroll
    for (int j = 0; j < VPL; ++j) {
        float v = acc[j] * inv_l + bias[lane * VPL + j];
        vals[j] = (v > 0.f) ? v : (__expf(v) - 1.f);
    }
    if (OUTF32) {
        float* out = (float*)out_v;
#pragma unroll
        for (int j = 0; j < VPL; ++j)
            out[(size_t)node * HC + lane * VPL + j] = vals[j];
    } else {
        unsigned short* out = (unsigned short*)out_v;
        if (VPL == 4) {
            ushort4 o;
            o.x = f2bf(vals[0]); o.y = f2bf(vals[1]);
            o.z = f2bf(vals[2]); o.w = f2bf(vals[3]);
            *(ushort4*)&out[(size_t)node * HC + lane * 4] = o;
        } else {
            out[(size_t)node * HC + lane] = f2bf(vals[0]);
        }
    }
}

// ============================ pool + classify ==============================
#define POOL_CHUNK 128
__global__ __launch_bounds__(256) void pool_kernel(const float* __restrict__ hf,
                                                   const int* __restrict__ batch,
                                                   float* __restrict__ sums,
                                                   float* __restrict__ counts, int N) {
    int t = threadIdx.x;
    int c = t & 63, sub = t >> 6;
    int start = blockIdx.x * POOL_CHUNK;
    int end = min(start + POOL_CHUNK, N);
    float acc = 0.f, cnt = 0.f;
    int cur = -1;
    for (int n = start + sub; n < end; n += 4) {
        int g = batch[n];
        if (g != cur) {
            if (cur >= 0) {
                atomicAdd(&sums[cur * 64 + c], acc);
                if (c == 0) atomicAdd(&counts[cur], cnt);
            }
            cur = g; acc = 0.f; cnt = 0.f;
        }
        acc += hf[(size_t)n * 64 + c];
        cnt += 1.f;
    }
    if (cur >= 0) {
        atomicAdd(&sums[cur * 64 + c], acc);
        if (c == 0) atomicAdd(&counts[cur], cnt);
    }
}

__global__ void classify(const float* __restrict__ sums, const float* __restrict__ counts,
                         const float* __restrict__ Wc, const float* __restrict__ bc,
                         float* __restrict__ out, int NC) {
    __shared__ float p[64];
    int g = blockIdx.x;
    if (threadIdx.x < 64) {
        float cnt = fmaxf(counts[g], 1.0f);
        p[threadIdx.x] = sums[g * 64 + threadIdx.x] / cnt;
    }
    __syncthreads();
    int k = threadIdx.x;
    if (k < NC) {
        float acc = bc[k];
        for (int c = 0; c < 64; ++c) acc += p[c] * Wc[c * NC + k];
        out[g * NC + k] = acc;
    }
}

static inline size_t align_up(size_t x, size_t a) { return (x + a - 1) / a * a; }

extern "C" void kernel_launch(void* const* d_in, const int* in_sizes, int n_in,
                              void* d_out, int out_size, void* d_ws, size_t ws_size,
                              hipStream_t stream) {
    const float* x      = (const float*)d_in[0];
    const int*   ei     = (const int*)d_in[1];
    const int*   batch  = (const int*)d_in[2];
    const float* W1     = (const float*)d_in[3];
    const float* a_src1 = (const float*)d_in[4];
    const float* a_dst1 = (const float*)d_in[5];
    const float* b1     = (const float*)d_in[6];
    const float* W2     = (const float*)d_in[7];
    const float* a_src2 = (const float*)d_in[8];
    const float* a_dst2 = (const float*)d_in[9];
    const float* b2     = (const float*)d_in[10];
    const float* W3     = (const float*)d_in[11];
    const float* a_src3 = (const float*)d_in[12];
    const float* a_dst3 = (const float*)d_in[13];
    const float* b3     = (const float*)d_in[14];
    const float* Wc     = (const float*)d_in[15];
    const float* bc     = (const float*)d_in[16];

    const int N    = in_sizes[2];
    const int E    = in_sizes[1] / 2;
    const int F_IN = in_sizes[0] / N;   // 128
    const int HC   = in_sizes[6];       // 256
    const int C    = in_sizes[14];      // 64
    const int NC   = in_sizes[16];      // 200
    const int Etot = E + N;
    const int NB   = (N + 1023) / 1024;
    const int NPB  = (N + POOL_CHUNK - 1) / POOL_CHUNK;

    char* w = (char*)d_ws;
    size_t off = 0;
    auto alloc = [&](size_t bytes) -> void* {
        void* p = w + off;
        off = align_up(off + bytes, 256);
        return p;
    };
    int*   deg    = (int*)alloc((size_t)N * 4);
    int*   rowptr = (int*)alloc((size_t)(N + 1) * 4);
    int*   fill   = (int*)alloc((size_t)N * 4);
    int*   srcs   = (int*)alloc((size_t)Etot * 4);
    int*   bsums  = (int*)alloc((size_t)NB * 4);
    float* as_buf = (float*)alloc((size_t)N * 4 * 4);
    float* ad_buf = (float*)alloc((size_t)N * 4 * 4);
    unsigned short* Wt1 = (unsigned short*)alloc((size_t)HC * F_IN * 2);
    unsigned short* Wt2 = (unsigned short*)alloc((size_t)HC * HC * 2);
    unsigned short* Wt3 = (unsigned short*)alloc((size_t)C * HC * 2);
    unsigned short* hA  = (unsigned short*)alloc((size_t)N * HC * 2);
    unsigned short* hB  = (unsigned short*)alloc((size_t)N * HC * 2);
    unsigned short* hC  = (unsigned short*)alloc((size_t)N * C * 2);
    float* bufF   = (float*)alloc((size_t)N * C * 4);
    float* sums   = (float*)alloc((size_t)(64 * 64 + 64) * 4);
    float* counts = sums + 64 * 64;

    const int TPB = 256;

    // ---- CSR build ----
    hipMemsetAsync(deg, 0, (size_t)N * 4, stream);
    hipMemsetAsync(fill, 0, (size_t)N * 4, stream);
    count_edges<<<(Etot + TPB - 1) / TPB, TPB, 0, stream>>>(ei, deg, E, N);
    scan_partial<<<NB, 256, 0, stream>>>(deg, rowptr, bsums, N);
    scan_blocks<<<1, 64, 0, stream>>>(bsums, rowptr, NB, N);
    add_offsets<<<(N + TPB - 1) / TPB, TPB, 0, stream>>>(rowptr, bsums, N);
    scatter_edges<<<(Etot + TPB - 1) / TPB, TPB, 0, stream>>>(ei, rowptr, fill, srcs, E, N);

    // ---- weight casts ----
    wcast<<<(HC * F_IN + TPB - 1) / TPB, TPB, 0, stream>>>(W1, Wt1, F_IN, HC);
    wcast<<<(HC * HC + TPB - 1) / TPB, TPB, 0, stream>>>(W2, Wt2, HC, HC);
    wcast<<<(C * HC + TPB - 1) / TPB, TPB, 0, stream>>>(W3, Wt3, HC, C);

    dim3 gWide((HC + BN - 1) / BN, (N + BM - 1) / BM);
    dim3 gNarrow((C + BN - 1) / BN, (N + BM - 1) / BM);
    int aggBlocks = (N + 1) / 2;

    // ---- Layer 1 (A = f32 x, converted in staging) ----
    gemm_bf16<true><<<gWide, 256, 0, stream>>>(x, Wt1, hA, a_src1, a_dst1, as_buf, ad_buf, N, HC, F_IN, 4);
    gat_aggregate<4, 4, false><<<aggBlocks, 256, 0, stream>>>(hA, as_buf, ad_buf, rowptr, srcs, b1, hB, N);

    // ---- Layer 2 ----
    gemm_bf16<false><<<gWide, 256, 0, stream>>>(hB, Wt2, hA, a_src2, a_dst2, as_buf, ad_buf, N, HC, HC, 4);
    gat_aggregate<4, 4, false><<<aggBlocks, 256, 0, stream>>>(hA, as_buf, ad_buf, rowptr, srcs, b2, hB, N);

    // ---- Layer 3 (H=1) ----
    gemm_bf16<false><<<gNarrow, 256, 0, stream>>>(hB, Wt3, hC, a_src3, a_dst3, as_buf, ad_buf, N, C, HC, 1);
    gat_aggregate<1, 1, true><<<aggBlocks, 256, 0, stream>>>(hC, as_buf, ad_buf, rowptr, srcs, b3, bufF, N);

    // ---- Pool + classify ----
    hipMemsetAsync(sums, 0, (size_t)(64 * 64 + 64) * 4, stream);
    pool_kernel<<<NPB, 256, 0, stream>>>(bufF, batch, sums, counts, N);
    classify<<<64, 256, 0, stream>>>(sums, counts, Wc, bc, (float*)d_out, NC);
}

// Round 8
// 485.730 us; speedup vs baseline: 1.0758x; 1.0758x over previous
//
#include <hip/hip_runtime.h>

// ---------------------------------------------------------------------------
// GAT 3-layer classifier, bf16 intermediate storage + MFMA GEMMs.
//   CSR build (count / multi-block scan / scatter) -- edges grouped by dst
//   per layer: mfma-gemm(h,W)+attn-coef epilogue -> single-pass aggregate
//   pool (sorted batch, chunked) -> classifier GEMM
// All math f32 in registers; h stored bf16 (manual RNE).
// R6: single-pass softmax (no max-shift; |e| O(1)), attn fused in GEMM.
// R7 (REVERTED): edge-split 2 waves/node pushed half the edges into the
//     serial scalar tail -> 68->81us. Kept: log2e fold, fused xcast.
// R8: one wave/node again, PREDICATED full unroll -- every edge processed
//     inside an 8-deep independent-gather round (clamped index + cndmask'd
//     weight); the ~3.5 serial tail iterations per node are gone.
// ---------------------------------------------------------------------------

typedef __attribute__((ext_vector_type(8))) __bf16 bf16x8;
typedef __attribute__((ext_vector_type(4))) float f32x4;

#define LOG2E 1.44269504f

static __device__ __forceinline__ unsigned short f2bf(float f) {
    unsigned u = __float_as_uint(f);
    unsigned r = (u + 0x7fffu + ((u >> 16) & 1u)) >> 16;
    return (unsigned short)r;
}
static __device__ __forceinline__ float bf2f(unsigned short s) {
    return __uint_as_float(((unsigned)s) << 16);
}

// ============================ CSR build ====================================
__global__ void count_edges(const int* __restrict__ ei, int* __restrict__ deg,
                            int E, int N) {
    int i = blockIdx.x * blockDim.x + threadIdx.x;
    int tot = E + N;
    if (i >= tot) return;
    int dst = (i < E) ? ei[E + i] : (i - E);
    atomicAdd(&deg[dst], 1);
}

__global__ __launch_bounds__(256) void scan_partial(const int* __restrict__ deg,
                                                    int* __restrict__ rowptr,
                                                    int* __restrict__ blockSums, int N) {
    int t = threadIdx.x;
    int lane = t & 63, wv = t >> 6;
    int base = blockIdx.x * 1024 + t * 4;
    int v[4];
#pragma unroll
    for (int j = 0; j < 4; ++j) v[j] = (base + j < N) ? deg[base + j] : 0;
    int local = v[0] + v[1] + v[2] + v[3];
    int x = local;
#pragma unroll
    for (int off = 1; off < 64; off <<= 1) {
        int y = __shfl_up(x, off);
        if (lane >= off) x += y;
    }
    __shared__ int wsum[4];
    if (lane == 63) wsum[wv] = x;
    __syncthreads();
    int woff = 0;
    for (int i = 0; i < wv; ++i) woff += wsum[i];
    int run = woff + x - local;
#pragma unroll
    for (int j = 0; j < 4; ++j) {
        if (base + j < N) rowptr[base + j] = run;
        run += v[j];
    }
    if (t == 255) blockSums[blockIdx.x] = woff + x;
}

__global__ void scan_blocks(int* __restrict__ blockSums, int* __restrict__ rowptr,
                            int NB, int N) {
    int lane = threadIdx.x;  // 64 threads
    int carry = 0;
    for (int b0 = 0; b0 < NB; b0 += 64) {
        int i = b0 + lane;
        int v = (i < NB) ? blockSums[i] : 0;
        int x = v;
#pragma unroll
        for (int off = 1; off < 64; off <<= 1) {
            int y = __shfl_up(x, off);
            if (lane >= off) x += y;
        }
        if (i < NB) blockSums[i] = carry + x - v;
        carry += __shfl(x, 63);
    }
    if (lane == 0) rowptr[N] = carry;
}

__global__ void add_offsets(int* __restrict__ rowptr, const int* __restrict__ blockOffs,
                            int N) {
    int i = blockIdx.x * blockDim.x + threadIdx.x;
    if (i < N) rowptr[i] += blockOffs[i >> 10];
}

__global__ void scatter_edges(const int* __restrict__ ei, const int* __restrict__ rowptr,
                              int* __restrict__ fill, int* __restrict__ srcs, int E, int N) {
    int i = blockIdx.x * blockDim.x + threadIdx.x;
    int tot = E + N;
    if (i >= tot) return;
    int src, dst;
    if (i < E) { src = ei[i]; dst = ei[E + i]; }
    else       { src = i - E; dst = i - E; }
    int pos = atomicAdd(&fill[dst], 1);
    srcs[rowptr[dst] + pos] = src;
}

// ============================ casts ========================================
// Wt[n*K+k] = bf16(W[k*N+n])
__global__ void wcast(const float* __restrict__ W, unsigned short* __restrict__ Wt,
                      int K, int N) {
    int i = blockIdx.x * blockDim.x + threadIdx.x;
    if (i >= N * K) return;
    int n = i / K, k = i - n * K;
    Wt[i] = f2bf(W[(size_t)k * N + n]);
}

// ============================ MFMA GEMM + attn epilogue ====================
// C[M,N](bf16) = A[M,K] @ Bt[N,K](bf16)^T.  AF32: A is f32, converted while
// staging (fuses the xcast).  128x128 tile, BK=32, 4 waves, 64x64/wave.
// Epilogue: wave's 64-col span == one head; as/ad dots from f32 accumulators,
// PRE-SCALED by log2(e) so the aggregate can use exp2.
#define BM 128
#define BN 128
#define BK 32
#define LDK 40  // padded row stride (elements); 80B, 16B-aligned

template <bool AF32>
__global__ __launch_bounds__(256) void gemm_bf16(const void* __restrict__ Av,
                                                 const unsigned short* __restrict__ Bt,
                                                 unsigned short* __restrict__ C,
                                                 const float* __restrict__ a_src,
                                                 const float* __restrict__ a_dst,
                                                 float* __restrict__ as_o,
                                                 float* __restrict__ ad_o,
                                                 int M, int N, int K, int H) {
    __shared__ unsigned short As[BM * LDK];
    __shared__ unsigned short Bs[BN * LDK];
    int t = threadIdx.x;
    int bm = blockIdx.y * BM, bn = blockIdx.x * BN;
    int wave = t >> 6, lane = t & 63;
    int wm = (wave >> 1) * 64, wn = (wave & 1) * 64;
    int quad = lane >> 4, mr = lane & 15;

    f32x4 zero = {0.f, 0.f, 0.f, 0.f};
    f32x4 acc[4][4];
#pragma unroll
    for (int i = 0; i < 4; ++i)
#pragma unroll
        for (int j = 0; j < 4; ++j) acc[i][j] = zero;

    for (int k0 = 0; k0 < K; k0 += BK) {
        ushort4 ua[2][2];   // staged A (bf16), 2 segs x 8 elems
        float4 vb[2];
#pragma unroll
        for (int h = 0; h < 2; ++h) {
            int s = t + h * 256;
            int row = s >> 2, seg = (s & 3) * 8;
            int gra = bm + row;
            if (AF32) {
                const float* Af = (const float*)Av;
                float4 lo = make_float4(0.f, 0.f, 0.f, 0.f), hi = lo;
                if (gra < M) {
                    lo = *(const float4*)&Af[(size_t)gra * K + k0 + seg];
                    hi = *(const float4*)&Af[(size_t)gra * K + k0 + seg + 4];
                }
                ua[h][0] = make_ushort4(f2bf(lo.x), f2bf(lo.y), f2bf(lo.z), f2bf(lo.w));
                ua[h][1] = make_ushort4(f2bf(hi.x), f2bf(hi.y), f2bf(hi.z), f2bf(hi.w));
            } else {
                const unsigned short* Ab = (const unsigned short*)Av;
                float4 va = make_float4(0.f, 0.f, 0.f, 0.f);
                if (gra < M) va = *(const float4*)&Ab[(size_t)gra * K + k0 + seg];
                ua[h][0] = *(ushort4*)&va.x;
                ua[h][1] = *(ushort4*)&va.z;
            }
            int grb = bn + row;
            vb[h] = make_float4(0.f, 0.f, 0.f, 0.f);
            if (grb < N) vb[h] = *(const float4*)&Bt[(size_t)grb * K + k0 + seg];
        }
        __syncthreads();
#pragma unroll
        for (int h = 0; h < 2; ++h) {
            int s = t + h * 256;
            int row = s >> 2, seg = (s & 3) * 8;
            *(ushort4*)&As[row * LDK + seg]     = ua[h][0];
            *(ushort4*)&As[row * LDK + seg + 4] = ua[h][1];
            *(float4*)&Bs[row * LDK + seg] = vb[h];
        }
        __syncthreads();

        bf16x8 af[4], bfr[4];
#pragma unroll
        for (int i = 0; i < 4; ++i) {
            af[i]  = *(bf16x8*)&As[(wm + i * 16 + mr) * LDK + quad * 8];
            bfr[i] = *(bf16x8*)&Bs[(wn + i * 16 + mr) * LDK + quad * 8];
        }
#pragma unroll
        for (int i = 0; i < 4; ++i)
#pragma unroll
            for (int j = 0; j < 4; ++j)
                acc[i][j] = __builtin_amdgcn_mfma_f32_16x16x32_bf16(af[i], bfr[j], acc[i][j], 0, 0, 0);
    }

    // attn coefficients: this wave's 64 cols == head (bn+wn)/64
    int colbase = bn + wn;
    if (colbase + 64 <= N) {
        int head = colbase >> 6;
        float asv[4], adv[4];
#pragma unroll
        for (int j = 0; j < 4; ++j) {
            asv[j] = a_src[head * 64 + j * 16 + mr];
            adv[j] = a_dst[head * 64 + j * 16 + mr];
        }
#pragma unroll
        for (int i = 0; i < 4; ++i) {
#pragma unroll
            for (int r = 0; r < 4; ++r) {
                float ps = acc[i][0][r] * asv[0] + acc[i][1][r] * asv[1]
                         + acc[i][2][r] * asv[2] + acc[i][3][r] * asv[3];
                float pd = acc[i][0][r] * adv[0] + acc[i][1][r] * adv[1]
                         + acc[i][2][r] * adv[2] + acc[i][3][r] * adv[3];
#pragma unroll
                for (int off2 = 1; off2 < 16; off2 <<= 1) {
                    ps += __shfl_xor(ps, off2);
                    pd += __shfl_xor(pd, off2);
                }
                int grow = bm + wm + i * 16 + quad * 4 + r;
                if (mr == 0 && grow < M) {
                    as_o[(size_t)grow * H + head] = ps * LOG2E;
                    ad_o[(size_t)grow * H + head] = pd * LOG2E;
                }
            }
        }
    }

    // C store: C/D layout col=lane&15, row=quad*4+reg
#pragma unroll
    for (int i = 0; i < 4; ++i) {
#pragma unroll
        for (int r = 0; r < 4; ++r) {
            int grow = bm + wm + i * 16 + quad * 4 + r;
            if (grow >= M) continue;
#pragma unroll
            for (int j = 0; j < 4; ++j) {
                int gcol = bn + wn + j * 16 + mr;
                if (gcol < N) C[(size_t)grow * N + gcol] = f2bf(acc[i][j][r]);
            }
        }
    }
}

// ============================ aggregation ==================================
// Single-pass unnormalized softmax: out = sum(exp(e)*h) / (sum(exp(e))+eps).
// as/ad pre-scaled by log2(e) -> exp2 in the hot loop.
// One wave per node. Predicated full unroll: every round issues 8
// independent gathers with clamped indices; out-of-range edges get wgt=0.
// No serial tail loop at all.
template <int H, int VPL, bool OUTF32>
__global__ __launch_bounds__(256) void gat_aggregate(const unsigned short* __restrict__ hbuf,
                                                     const float* __restrict__ as_i,
                                                     const float* __restrict__ ad_i,
                                                     const int* __restrict__ rowptr,
                                                     const int* __restrict__ srcs,
                                                     const float* __restrict__ bias,
                                                     void* __restrict__ out_v, int N) {
    const int HC = 64 * VPL;
    int node = (blockIdx.x * blockDim.x + threadIdx.x) >> 6;
    int lane = threadIdx.x & 63;
    if (node >= N) return;
    int row = rowptr[node], end = rowptr[node + 1];
    int len = end - row;
    const int hd_lane = (lane * VPL) >> 6;

    float advh = ad_i[(size_t)node * H + hd_lane];

    float acc[VPL];
#pragma unroll
    for (int j = 0; j < VPL; ++j) acc[j] = 0.f;
    float l = 0.f;

    const int U = 8;
    for (int base = 0; base < len; base += U) {
        int s[U];
        float cf[U];
#pragma unroll
        for (int u = 0; u < U; ++u) {
            int idx = base + u;
            int ii = row + ((idx < len) ? idx : (len - 1));
            s[u] = srcs[ii];
        }
#pragma unroll
        for (int u = 0; u < U; ++u) cf[u] = as_i[(size_t)s[u] * H + hd_lane];
        if (VPL == 4) {
            ushort4 r[U];
#pragma unroll
            for (int u = 0; u < U; ++u)
                r[u] = *(const ushort4*)&hbuf[(size_t)s[u] * HC + lane * 4];
#pragma unroll
            for (int u = 0; u < U; ++u) {
                float e = cf[u] + advh;
                e = (e > 0.f) ? e : 0.2f * e;
                float wgt = (base + u < len) ? exp2f(e) : 0.f;
                l += wgt;
                acc[0] += wgt * bf2f(r[u].x);
                acc[1] += wgt * bf2f(r[u].y);
                acc[2] += wgt * bf2f(r[u].z);
                acc[3] += wgt * bf2f(r[u].w);
            }
        } else {
            unsigned short r[U];
#pragma unroll
            for (int u = 0; u < U; ++u) r[u] = hbuf[(size_t)s[u] * HC + lane];
#pragma unroll
            for (int u = 0; u < U; ++u) {
                float e = cf[u] + advh;
                e = (e > 0.f) ? e : 0.2f * e;
                float wgt = (base + u < len) ? exp2f(e) : 0.f;
                l += wgt;
                acc[0] += wgt * bf2f(r[u]);
            }
        }
    }

    float inv_l = 1.f / (l + 1e-16f);
    float vals[VPL];
#pragma unroll
    for (int j = 0; j < VPL; ++j) {
        float v = acc[j] * inv_l + bias[lane * VPL + j];
        vals[j] = (v > 0.f) ? v : (__expf(v) - 1.f);
    }
    if (OUTF32) {
        float* out = (float*)out_v;
#pragma unroll
        for (int j = 0; j < VPL; ++j)
            out[(size_t)node * HC + lane * VPL + j] = vals[j];
    } else {
        unsigned short* out = (unsigned short*)out_v;
        if (VPL == 4) {
            ushort4 o;
            o.x = f2bf(vals[0]); o.y = f2bf(vals[1]);
            o.z = f2bf(vals[2]); o.w = f2bf(vals[3]);
            *(ushort4*)&out[(size_t)node * HC + lane * 4] = o;
        } else {
            out[(size_t)node * HC + lane] = f2bf(vals[0]);
        }
    }
}

// ============================ pool + classify ==============================
#define POOL_CHUNK 128
__global__ __launch_bounds__(256) void pool_kernel(const float* __restrict__ hf,
                                                   const int* __restrict__ batch,
                                                   float* __restrict__ sums,
                                                   float* __restrict__ counts, int N) {
    int t = threadIdx.x;
    int c = t & 63, sub = t >> 6;
    int start = blockIdx.x * POOL_CHUNK;
    int end = min(start + POOL_CHUNK, N);
    float acc = 0.f, cnt = 0.f;
    int cur = -1;
    for (int n = start + sub; n < end; n += 4) {
        int g = batch[n];
        if (g != cur) {
            if (cur >= 0) {
                atomicAdd(&sums[cur * 64 + c], acc);
                if (c == 0) atomicAdd(&counts[cur], cnt);
            }
            cur = g; acc = 0.f; cnt = 0.f;
        }
        acc += hf[(size_t)n * 64 + c];
        cnt += 1.f;
    }
    if (cur >= 0) {
        atomicAdd(&sums[cur * 64 + c], acc);
        if (c == 0) atomicAdd(&counts[cur], cnt);
    }
}

__global__ void classify(const float* __restrict__ sums, const float* __restrict__ counts,
                         const float* __restrict__ Wc, const float* __restrict__ bc,
                         float* __restrict__ out, int NC) {
    __shared__ float p[64];
    int g = blockIdx.x;
    if (threadIdx.x < 64) {
        float cnt = fmaxf(counts[g], 1.0f);
        p[threadIdx.x] = sums[g * 64 + threadIdx.x] / cnt;
    }
    __syncthreads();
    int k = threadIdx.x;
    if (k < NC) {
        float acc = bc[k];
        for (int c = 0; c < 64; ++c) acc += p[c] * Wc[c * NC + k];
        out[g * NC + k] = acc;
    }
}

static inline size_t align_up(size_t x, size_t a) { return (x + a - 1) / a * a; }

extern "C" void kernel_launch(void* const* d_in, const int* in_sizes, int n_in,
                              void* d_out, int out_size, void* d_ws, size_t ws_size,
                              hipStream_t stream) {
    const float* x      = (const float*)d_in[0];
    const int*   ei     = (const int*)d_in[1];
    const int*   batch  = (const int*)d_in[2];
    const float* W1     = (const float*)d_in[3];
    const float* a_src1 = (const float*)d_in[4];
    const float* a_dst1 = (const float*)d_in[5];
    const float* b1     = (const float*)d_in[6];
    const float* W2     = (const float*)d_in[7];
    const float* a_src2 = (const float*)d_in[8];
    const float* a_dst2 = (const float*)d_in[9];
    const float* b2     = (const float*)d_in[10];
    const float* W3     = (const float*)d_in[11];
    const float* a_src3 = (const float*)d_in[12];
    const float* a_dst3 = (const float*)d_in[13];
    const float* b3     = (const float*)d_in[14];
    const float* Wc     = (const float*)d_in[15];
    const float* bc     = (const float*)d_in[16];

    const int N    = in_sizes[2];
    const int E    = in_sizes[1] / 2;
    const int F_IN = in_sizes[0] / N;   // 128
    const int HC   = in_sizes[6];       // 256
    const int C    = in_sizes[14];      // 64
    const int NC   = in_sizes[16];      // 200
    const int Etot = E + N;
    const int NB   = (N + 1023) / 1024;
    const int NPB  = (N + POOL_CHUNK - 1) / POOL_CHUNK;

    char* w = (char*)d_ws;
    size_t off = 0;
    auto alloc = [&](size_t bytes) -> void* {
        void* p = w + off;
        off = align_up(off + bytes, 256);
        return p;
    };
    int*   deg    = (int*)alloc((size_t)N * 4);
    int*   rowptr = (int*)alloc((size_t)(N + 1) * 4);
    int*   fill   = (int*)alloc((size_t)N * 4);
    int*   srcs   = (int*)alloc((size_t)Etot * 4);
    int*   bsums  = (int*)alloc((size_t)NB * 4);
    float* as_buf = (float*)alloc((size_t)N * 4 * 4);
    float* ad_buf = (float*)alloc((size_t)N * 4 * 4);
    unsigned short* Wt1 = (unsigned short*)alloc((size_t)HC * F_IN * 2);
    unsigned short* Wt2 = (unsigned short*)alloc((size_t)HC * HC * 2);
    unsigned short* Wt3 = (unsigned short*)alloc((size_t)C * HC * 2);
    unsigned short* hA  = (unsigned short*)alloc((size_t)N * HC * 2);
    unsigned short* hB  = (unsigned short*)alloc((size_t)N * HC * 2);
    unsigned short* hC  = (unsigned short*)alloc((size_t)N * C * 2);
    float* bufF   = (float*)alloc((size_t)N * C * 4);
    float* sums   = (float*)alloc((size_t)(64 * 64 + 64) * 4);
    float* counts = sums + 64 * 64;

    const int TPB = 256;

    // ---- CSR build ----
    hipMemsetAsync(deg, 0, (size_t)N * 4, stream);
    hipMemsetAsync(fill, 0, (size_t)N * 4, stream);
    count_edges<<<(Etot + TPB - 1) / TPB, TPB, 0, stream>>>(ei, deg, E, N);
    scan_partial<<<NB, 256, 0, stream>>>(deg, rowptr, bsums, N);
    scan_blocks<<<1, 64, 0, stream>>>(bsums, rowptr, NB, N);
    add_offsets<<<(N + TPB - 1) / TPB, TPB, 0, stream>>>(rowptr, bsums, N);
    scatter_edges<<<(Etot + TPB - 1) / TPB, TPB, 0, stream>>>(ei, rowptr, fill, srcs, E, N);

    // ---- weight casts ----
    wcast<<<(HC * F_IN + TPB - 1) / TPB, TPB, 0, stream>>>(W1, Wt1, F_IN, HC);
    wcast<<<(HC * HC + TPB - 1) / TPB, TPB, 0, stream>>>(W2, Wt2, HC, HC);
    wcast<<<(C * HC + TPB - 1) / TPB, TPB, 0, stream>>>(W3, Wt3, HC, C);

    dim3 gWide((HC + BN - 1) / BN, (N + BM - 1) / BM);
    dim3 gNarrow((C + BN - 1) / BN, (N + BM - 1) / BM);
    int waveBlocks = (N + 3) / 4;

    // ---- Layer 1 (A = f32 x, converted in staging) ----
    gemm_bf16<true><<<gWide, 256, 0, stream>>>(x, Wt1, hA, a_src1, a_dst1, as_buf, ad_buf, N, HC, F_IN, 4);
    gat_aggregate<4, 4, false><<<waveBlocks, 256, 0, stream>>>(hA, as_buf, ad_buf, rowptr, srcs, b1, hB, N);

    // ---- Layer 2 ----
    gemm_bf16<false><<<gWide, 256, 0, stream>>>(hB, Wt2, hA, a_src2, a_dst2, as_buf, ad_buf, N, HC, HC, 4);
    gat_aggregate<4, 4, false><<<waveBlocks, 256, 0, stream>>>(hA, as_buf, ad_buf, rowptr, srcs, b2, hB, N);

    // ---- Layer 3 (H=1) ----
    gemm_bf16<false><<<gNarrow, 256, 0, stream>>>(hB, Wt3, hC, a_src3, a_dst3, as_buf, ad_buf, N, C, HC, 1);
    gat_aggregate<1, 1, true><<<waveBlocks, 256, 0, stream>>>(hC, as_buf, ad_buf, rowptr, srcs, b3, bufF, N);

    // ---- Pool + classify ----
    hipMemsetAsync(sums, 0, (size_t)(64 * 64 + 64) * 4, stream);
    pool_kernel<<<NPB, 256, 0, stream>>>(bufF, batch, sums, counts, N);
    classify<<<64, 256, 0, stream>>>(sums, counts, Wc, bc, (float*)d_out, NC);
}